// Round 6
// baseline (219.862 us; speedup 1.0000x reference)
//
#include <hip/hip_runtime.h>

#define C_IN   64
#define C_OUT  128
#define Himg   128
#define Wimg   128
#define HW     (Himg * Wimg)
#define TROWS  8
#define TCOLS  32
#define HROWS  10   // TROWS+2
#define HCOLS  34   // TCOLS+2
#define XCELLS (HROWS * HCOLS)      // 340 pixel cells per k-group
#define XKSTR  (XCELLS * 16)        // 5440 B: Xs k-group stride

typedef __bf16 bf16x8 __attribute__((ext_vector_type(8)));
typedef float  f32x16 __attribute__((ext_vector_type(16)));

__device__ __forceinline__ unsigned int pack2(float a, float b) {
  union { __bf16 h; unsigned short s; } ua, ub;
  ua.h = (__bf16)a; ub.h = (__bf16)b;
  return (unsigned int)ua.s | ((unsigned int)ub.s << 16);
}

// fp32 W[co][c][3][3] -> bf16 wt, k-major 16B cells: wt[tap][c>>3][co][c&7]
__global__ void wt_transform(const float* __restrict__ w, unsigned short* __restrict__ wt) {
  const int idx = blockIdx.x * 256 + threadIdx.x;
  if (idx >= 9 * C_OUT * C_IN) return;
  const int c   = idx & 63;
  const int co  = (idx >> 6) & 127;
  const int tap = idx >> 13;
  const int ky = tap / 3, kx = tap % 3;
  const float f = w[((co * C_IN + c) * 3 + ky) * 3 + kx];
  union { __bf16 h; unsigned short s; } u; u.h = (__bf16)f;
  wt[tap * 8192 + (c >> 3) * 1024 + co * 8 + (c & 7)] = u.s;
}

__global__ __launch_bounds__(512, 4)
void conv_mfma(const float* __restrict__ xin, const unsigned short* __restrict__ wt,
               const float* __restrict__ bias, float* __restrict__ out) {
  __shared__ __align__(16) unsigned char Xs[8 * XKSTR];    // 43520: [kgrp][pixel] 16B cells

  const int tid = threadIdx.x;
  // bijective XCD swizzle: 2304 = 8 * 288
  const int wg  = (blockIdx.x & 7) * 288 + (blockIdx.x >> 3);
  const int bx  = wg & 3;
  const int by  = (wg >> 2) & 15;
  const int img = wg >> 6;
  const int gy0 = by * TROWS;
  const int gx0 = bx * TCOLS;
  const int lane = tid & 63;

  // ---- stage X tile interior (fp32 -> bf16), storage pixel cols 1..32 ----
  {
    const int xi = tid & 31;                 // x offset within tile
    const int cq = tid >> 5;                 // 0..15 -> 4 channels each
    const int c0 = cq * 4;
    const int kg = c0 >> 3;
    const int bo = (c0 & 7) * 2;             // 0 or 8 within the 16B cell
    const float* pbase = xin + ((size_t)img * C_IN + c0) * HW + gx0 + xi;
    #pragma unroll
    for (int r = 0; r < HROWS; ++r) {
      const int gy = gy0 - 1 + r;
      float f0 = 0.f, f1 = 0.f, f2 = 0.f, f3 = 0.f;
      if (gy >= 0 && gy < Himg) {
        const float* p = pbase + (size_t)gy * Wimg;
        f0 = p[0];
        f1 = p[HW];
        f2 = p[2 * HW];
        f3 = p[3 * HW];
      }
      const int pix = r * HCOLS + 1 + xi;
      *(uint2*)(&Xs[kg * XKSTR + pix * 16 + bo]) = make_uint2(pack2(f0, f1), pack2(f2, f3));
    }
  }
  // ---- halo columns (pixel col 0 and 33) ----
  for (int idx = tid; idx < 2 * HROWS * C_IN; idx += 512) {
    const int side = (idx >= HROWS * C_IN) ? 1 : 0;
    const int rem  = idx - side * HROWS * C_IN;
    const int c = rem & 63;
    const int r = rem >> 6;
    const int gy = gy0 - 1 + r;
    const int gx = side ? (gx0 + TCOLS) : (gx0 - 1);
    float f = 0.f;
    if (gy >= 0 && gy < Himg && gx >= 0 && gx < Wimg)
      f = xin[((size_t)img * C_IN + c) * HW + (size_t)gy * Wimg + gx];
    const int pix = r * HCOLS + (side ? (HCOLS - 1) : 0);
    union { __bf16 h; unsigned short s; } u; u.h = (__bf16)f;
    *(unsigned short*)(&Xs[(c >> 3) * XKSTR + pix * 16 + (c & 7) * 2]) = u.s;
  }

  // wave tile: 64 co x 64 px (2 rows of 32)
  const int lpx = lane & 31;
  const int lkh = lane >> 5;
  const int wv  = tid >> 6;       // 0..7
  const int wm  = wv & 1;         // co half
  const int wr  = wv >> 1;        // px quarter: rows wr*2, wr*2+1

  f32x16 acc[2][2];
  #pragma unroll
  for (int mf = 0; mf < 2; ++mf)
    #pragma unroll
    for (int nf = 0; nf < 2; ++nf)
      acc[mf][nf] = (f32x16)(0.f);

  // A frag (global, L2-hot): wt[tap][ks*2+lkh][wm*64+mf*32+lpx][0..7]
  const unsigned short* wl = wt + lkh * 1024 + (wm * 64 + lpx) * 8;
  const int xbase = lkh * XKSTR;   // + ks*2*XKSTR + pix*16

  __syncthreads();   // Xs ready; read-only hereafter; NO further barriers

  for (int t = 0; t < 9; ++t) {
    const int dy = (t >= 6) ? 2 : (t >= 3 ? 1 : 0);
    const int dx = t - dy * 3;
    const unsigned short* wtap = wl + t * 8192;
    int boff[2];
    #pragma unroll
    for (int nf = 0; nf < 2; ++nf)
      boff[nf] = xbase + ((wr * 2 + nf + dy) * HCOLS + dx + lpx) * 16;
    #pragma unroll
    for (int sh = 0; sh < 2; ++sh) {   // k-steps in batches of 2 to bound live regs
      bf16x8 A[2][2], B[2][2];
      #pragma unroll
      for (int ss = 0; ss < 2; ++ss) {
        const int ks = sh * 2 + ss;
        #pragma unroll
        for (int mf = 0; mf < 2; ++mf)
          A[mf][ss] = *(const bf16x8*)(wtap + ks * 2048 + mf * 256);
        #pragma unroll
        for (int nf = 0; nf < 2; ++nf)
          B[nf][ss] = *(const bf16x8*)&Xs[boff[nf] + ks * 2 * XKSTR];
      }
      #pragma unroll
      for (int ss = 0; ss < 2; ++ss)
        #pragma unroll
        for (int mf = 0; mf < 2; ++mf)
          #pragma unroll
          for (int nf = 0; nf < 2; ++nf)
            acc[mf][nf] = __builtin_amdgcn_mfma_f32_32x32x16_bf16(A[mf][ss], B[nf][ss], acc[mf][nf], 0, 0, 0);
    }
  }

  // ---- epilogue: bias + fp32 full-line nontemporal stores ----
  float4 bq[2][4];
  #pragma unroll
  for (int mf = 0; mf < 2; ++mf)
    #pragma unroll
    for (int rq = 0; rq < 4; ++rq)
      bq[mf][rq] = *(const float4*)(bias + wm * 64 + mf * 32 + rq * 8 + lkh * 4);

  #pragma unroll
  for (int nf = 0; nf < 2; ++nf) {
    const int y = gy0 + wr * 2 + nf;
    float* op = out + (size_t)img * C_OUT * HW + (size_t)y * Wimg + gx0 + lpx;
    #pragma unroll
    for (int mf = 0; mf < 2; ++mf) {
      #pragma unroll
      for (int r = 0; r < 16; ++r) {
        const int co = wm * 64 + mf * 32 + (r & 3) + 8 * (r >> 2) + lkh * 4;
        __builtin_nontemporal_store(acc[mf][nf][r] + ((const float*)&bq[mf][r >> 2])[r & 3],
                                    op + (size_t)co * HW);
      }
    }
  }
}

extern "C" void kernel_launch(void* const* d_in, const int* in_sizes, int n_in,
                              void* d_out, int out_size, void* d_ws, size_t ws_size,
                              hipStream_t stream) {
  const float* x    = (const float*)d_in[0];
  const float* w    = (const float*)d_in[1];
  const float* bias = (const float*)d_in[2];
  float* out = (float*)d_out;
  unsigned short* wt = (unsigned short*)d_ws;  // 9*8192 bf16 = 144 KB

  wt_transform<<<(9 * C_OUT * C_IN + 255) / 256, 256, 0, stream>>>(w, wt);

  conv_mfma<<<dim3(2304), 512, 0, stream>>>(x, wt, bias, out);
}

// Round 7
// 177.289 us; speedup vs baseline: 1.2401x; 1.2401x over previous
//
#include <hip/hip_runtime.h>

#define C_IN   64
#define C_OUT  128
#define Himg   128
#define Wimg   128
#define HW     (Himg * Wimg)
#define TROWS  4
#define TCOLS  32
#define HROWS  6    // TROWS+2
#define HCOLS  34   // TCOLS+2
#define XCELLS (HROWS * HCOLS)      // 204 pixel cells per k-group
#define XKSTR  (XCELLS * 16)        // 3264 B: Xs k-group stride

typedef __bf16 bf16x8 __attribute__((ext_vector_type(8)));
typedef float  f32x16 __attribute__((ext_vector_type(16)));

__device__ __forceinline__ unsigned int pack2(float a, float b) {
  union { __bf16 h; unsigned short s; } ua, ub;
  ua.h = (__bf16)a; ub.h = (__bf16)b;
  return (unsigned int)ua.s | ((unsigned int)ub.s << 16);
}

// fp32 W[co][c][3][3] -> bf16 wt, k-major 16B cells: wt[tap][c>>3][co][c&7]
__global__ void wt_transform(const float* __restrict__ w, unsigned short* __restrict__ wt) {
  const int idx = blockIdx.x * 256 + threadIdx.x;
  if (idx >= 9 * C_OUT * C_IN) return;
  const int c   = idx & 63;
  const int co  = (idx >> 6) & 127;
  const int tap = idx >> 13;
  const int ky = tap / 3, kx = tap % 3;
  const float f = w[((co * C_IN + c) * 3 + ky) * 3 + kx];
  union { __bf16 h; unsigned short s; } u; u.h = (__bf16)f;
  wt[tap * 8192 + (c >> 3) * 1024 + co * 8 + (c & 7)] = u.s;
}

// Prefetch A-fragments for (tap T, k-half SH) into parity buffer P
#define LOADA(P, T, SH)                                                              \
  {                                                                                  \
    _Pragma("unroll")                                                                \
    for (int mf_ = 0; mf_ < 2; ++mf_)                                                \
      _Pragma("unroll")                                                              \
      for (int ss_ = 0; ss_ < 2; ++ss_)                                              \
        Abuf[P][mf_][ss_] = *(const bf16x8*)(wl + (T) * 8192 + ((SH) * 2 + ss_) * 2048 + mf_ * 256); \
  }

__global__ __launch_bounds__(256, 3)
void conv_mfma(const float* __restrict__ xin, const unsigned short* __restrict__ wt,
               const float* __restrict__ bias, float* __restrict__ out) {
  __shared__ __align__(16) unsigned char Xs[8 * XKSTR];   // 26112: [kgrp][pixel] 16B cells

  const int tid = threadIdx.x;
  // bijective XCD swizzle: 4608 = 8 * 576
  const int wg  = (blockIdx.x & 7) * 576 + (blockIdx.x >> 3);
  const int bx  = wg & 3;
  const int by  = (wg >> 2) & 31;
  const int img = wg >> 7;
  const int gy0 = by * TROWS;
  const int gx0 = bx * TCOLS;
  const int lane = tid & 63;

  // ---- stage X tile interior (fp32 -> bf16), storage pixel cols 1..32 ----
  {
    const int xi = tid & 31;                 // x offset within tile
    const int cq = tid >> 5;                 // 0..7 -> 8 channels each = one 16B cell
    const float* pbase = xin + ((size_t)img * C_IN + cq * 8) * HW + gx0 + xi;
    #pragma unroll
    for (int r = 0; r < HROWS; ++r) {
      const int gy = gy0 - 1 + r;
      float f[8] = {0.f, 0.f, 0.f, 0.f, 0.f, 0.f, 0.f, 0.f};
      if (gy >= 0 && gy < Himg) {
        const float* p = pbase + (size_t)gy * Wimg;
        #pragma unroll
        for (int j = 0; j < 8; ++j) f[j] = p[(size_t)j * HW];
      }
      const int pix = r * HCOLS + 1 + xi;
      uint4 cell;
      cell.x = pack2(f[0], f[1]); cell.y = pack2(f[2], f[3]);
      cell.z = pack2(f[4], f[5]); cell.w = pack2(f[6], f[7]);
      *(uint4*)(&Xs[cq * XKSTR + pix * 16]) = cell;
    }
  }
  // ---- halo columns (pixel col 0 and 33): 2*6*64 = 768 items ----
  #pragma unroll
  for (int it = 0; it < 3; ++it) {
    const int idx = tid + it * 256;
    const int side = (idx >= HROWS * C_IN) ? 1 : 0;
    const int rem  = idx - side * HROWS * C_IN;
    const int c = rem & 63;
    const int r = rem >> 6;
    const int gy = gy0 - 1 + r;
    const int gx = side ? (gx0 + TCOLS) : (gx0 - 1);
    float f = 0.f;
    if (gy >= 0 && gy < Himg && gx >= 0 && gx < Wimg)
      f = xin[((size_t)img * C_IN + c) * HW + (size_t)gy * Wimg + gx];
    const int pix = r * HCOLS + (side ? (HCOLS - 1) : 0);
    union { __bf16 h; unsigned short s; } u; u.h = (__bf16)f;
    *(unsigned short*)(&Xs[(c >> 3) * XKSTR + pix * 16 + (c & 7) * 2]) = u.s;
  }

  // wave tile: 64 co (wm half) x 64 px (rows wn*2, wn*2+1)
  const int lpx = lane & 31;
  const int lkh = lane >> 5;
  const int wv  = tid >> 6;
  const int wm  = wv & 1;
  const int wn  = wv >> 1;

  f32x16 acc[2][2];
  #pragma unroll
  for (int mf = 0; mf < 2; ++mf)
    #pragma unroll
    for (int nf = 0; nf < 2; ++nf)
      acc[mf][nf] = (f32x16)(0.f);

  // A (global, L2-hot): wt[tap][(ksg*2+lkh)][wm*64+mf*32+lpx][0..7]
  const unsigned short* wl = wt + lkh * 1024 + (wm * 64 + lpx) * 8;
  // B (LDS): Xs[(ksg*2+lkh)][row*34 + dx + lpx]
  const int xb = lkh * XKSTR + lpx * 16;

  bf16x8 Abuf[2][2][2];   // [parity][mf][ss]
  LOADA(0, 0, 0)          // preload iteration 0 while barrier settles

  __syncthreads();   // Xs ready; read-only hereafter; no further barriers

  #pragma unroll
  for (int i = 0; i < 18; ++i) {           // i = tap*2 + sh
    if (i < 17) { LOADA((i + 1) & 1, (i + 1) >> 1, (i + 1) & 1) }
    const int t  = i >> 1, sh = i & 1;
    const int dy = (t >= 6) ? 2 : (t >= 3 ? 1 : 0);
    const int dx = t - dy * 3;
    bf16x8 B[2][2];
    #pragma unroll
    for (int nf = 0; nf < 2; ++nf) {
      const int cbase = ((wn * 2 + nf + dy) * HCOLS + dx) * 16;
      #pragma unroll
      for (int ss = 0; ss < 2; ++ss)
        B[nf][ss] = *(const bf16x8*)&Xs[xb + cbase + (sh * 2 + ss) * 2 * XKSTR];
    }
    #pragma unroll
    for (int ss = 0; ss < 2; ++ss)
      #pragma unroll
      for (int mf = 0; mf < 2; ++mf)
        #pragma unroll
        for (int nf = 0; nf < 2; ++nf)
          acc[mf][nf] = __builtin_amdgcn_mfma_f32_32x32x16_bf16(Abuf[i & 1][mf][ss], B[nf][ss], acc[mf][nf], 0, 0, 0);
  }

  // ---- epilogue: bias + fp32 full-line stores ----
  float4 bq[2][4];
  #pragma unroll
  for (int mf = 0; mf < 2; ++mf)
    #pragma unroll
    for (int rq = 0; rq < 4; ++rq)
      bq[mf][rq] = *(const float4*)(bias + wm * 64 + mf * 32 + rq * 8 + lkh * 4);

  #pragma unroll
  for (int nf = 0; nf < 2; ++nf) {
    const int y = gy0 + wn * 2 + nf;
    float* op = out + (size_t)img * C_OUT * HW + (size_t)y * Wimg + gx0 + lpx;
    #pragma unroll
    for (int mf = 0; mf < 2; ++mf) {
      #pragma unroll
      for (int r = 0; r < 16; ++r) {
        const int co = wm * 64 + mf * 32 + (r & 3) + 8 * (r >> 2) + lkh * 4;
        op[(size_t)co * HW] = acc[mf][nf][r] + ((const float*)&bq[mf][r >> 2])[r & 3];
      }
    }
  }
}

extern "C" void kernel_launch(void* const* d_in, const int* in_sizes, int n_in,
                              void* d_out, int out_size, void* d_ws, size_t ws_size,
                              hipStream_t stream) {
  const float* x    = (const float*)d_in[0];
  const float* w    = (const float*)d_in[1];
  const float* bias = (const float*)d_in[2];
  float* out = (float*)d_out;
  unsigned short* wt = (unsigned short*)d_ws;  // 9*8192 bf16 = 144 KB

  wt_transform<<<(9 * C_OUT * C_IN + 255) / 256, 256, 0, stream>>>(w, wt);

  conv_mfma<<<dim3(4608), 256, 0, stream>>>(x, wt, bias, out);
}

// Round 8
// 153.128 us; speedup vs baseline: 1.4358x; 1.1578x over previous
//
#include <hip/hip_runtime.h>

#define C_IN   64
#define C_OUT  128
#define Himg   128
#define Wimg   128
#define HW     (Himg * Wimg)
#define TROWS  8
#define TCOLS  32
#define HROWS  10   // TROWS+2
#define HCOLS  34   // TCOLS+2
#define XCELLS (HROWS * HCOLS)      // 340 pixel cells per k-group
#define XKSTR  (XCELLS * 16)        // 5440 B: Xs k-group stride
#define WS_TAP 16384

typedef __bf16 bf16x8 __attribute__((ext_vector_type(8)));
typedef float  f32x16 __attribute__((ext_vector_type(16)));

__device__ __forceinline__ unsigned int pack2(float a, float b) {
  union { __bf16 h; unsigned short s; } ua, ub;
  ua.h = (__bf16)a; ub.h = (__bf16)b;
  return (unsigned int)ua.s | ((unsigned int)ub.s << 16);
}

__device__ __forceinline__ void gload_lds16(const void* g, void* l) {
  __builtin_amdgcn_global_load_lds((const __attribute__((address_space(1))) void*)g,
                                   (__attribute__((address_space(3))) void*)l, 16, 0, 0);
}

// fp32 W[co][c][3][3] -> bf16 wt, k-major 16B cells: wt[tap][c>>3][co][c&7]
__global__ void wt_transform(const float* __restrict__ w, unsigned short* __restrict__ wt) {
  const int idx = blockIdx.x * 256 + threadIdx.x;
  if (idx >= 9 * C_OUT * C_IN) return;
  const int c   = idx & 63;
  const int co  = (idx >> 6) & 127;
  const int tap = idx >> 13;
  const int ky = tap / 3, kx = tap % 3;
  const float f = w[((co * C_IN + c) * 3 + ky) * 3 + kx];
  union { __bf16 h; unsigned short s; } u; u.h = (__bf16)f;
  wt[tap * 8192 + (c >> 3) * 1024 + co * 8 + (c & 7)] = u.s;
}

__global__ __launch_bounds__(512, 4)
void conv_mfma(const float* __restrict__ xin, const unsigned short* __restrict__ wt,
               const float* __restrict__ bias, float* __restrict__ out) {
  __shared__ __align__(16) unsigned char Xs[8 * XKSTR];    // 43520: [kgrp][pixel] 16B cells
  __shared__ __align__(16) unsigned char Ws[2][WS_TAP];    // 32768: [kidx][co] 16B cells

  const int tid = threadIdx.x;
  // bijective XCD swizzle: 2304 = 8 * 288
  const int wg  = (blockIdx.x & 7) * 288 + (blockIdx.x >> 3);
  const int bx  = wg & 3;
  const int by  = (wg >> 2) & 15;
  const int img = wg >> 6;
  const int gy0 = by * TROWS;
  const int gx0 = bx * TCOLS;
  const int lane = tid & 63;
  const int wv   = tid >> 6;    // 0..7

  // ---- issue async Ws tap-0 staging; X staging below covers its latency ----
  {
    const unsigned short* s0 = wt + lane * 8;
    #pragma unroll
    for (int j = 0; j < 2; ++j) {
      const int i = wv * 2 + j;
      gload_lds16(s0 + i * 512, &Ws[0][i * 1024]);
    }
  }

  // ---- stage X tile interior (fp32 -> bf16), storage pixel cols 1..32 ----
  {
    const int xi = tid & 31;                 // x offset within tile
    const int cq = tid >> 5;                 // 0..15 -> 4 channels each
    const int c0 = cq * 4;
    const int kg = c0 >> 3;                  // k-group row
    const int bo = (c0 & 7) * 2;             // 0 or 8 within the 16B cell
    const float* pbase = xin + ((size_t)img * C_IN + c0) * HW + gx0 + xi;
    #pragma unroll
    for (int r = 0; r < HROWS; ++r) {
      const int gy = gy0 - 1 + r;
      float f0 = 0.f, f1 = 0.f, f2 = 0.f, f3 = 0.f;
      if (gy >= 0 && gy < Himg) {
        const float* p = pbase + (size_t)gy * Wimg;
        f0 = p[0];
        f1 = p[HW];
        f2 = p[2 * HW];
        f3 = p[3 * HW];
      }
      const int pix = r * HCOLS + 1 + xi;
      *(uint2*)(&Xs[kg * XKSTR + pix * 16 + bo]) = make_uint2(pack2(f0, f1), pack2(f2, f3));
    }
  }
  // ---- halo columns (pixel col 0 and 33): 2*10*64 = 1280 items ----
  #pragma unroll
  for (int it = 0; it < 3; ++it) {
    const int idx = tid + it * 512;
    if (idx < 2 * HROWS * C_IN) {
      const int side = (idx >= HROWS * C_IN) ? 1 : 0;
      const int rem  = idx - side * HROWS * C_IN;
      const int c = rem & 63;
      const int r = rem >> 6;
      const int gy = gy0 - 1 + r;
      const int gx = side ? (gx0 + TCOLS) : (gx0 - 1);
      float f = 0.f;
      if (gy >= 0 && gy < Himg && gx >= 0 && gx < Wimg)
        f = xin[((size_t)img * C_IN + c) * HW + (size_t)gy * Wimg + gx];
      const int pix = r * HCOLS + (side ? (HCOLS - 1) : 0);
      union { __bf16 h; unsigned short s; } u; u.h = (__bf16)f;
      *(unsigned short*)(&Xs[(c >> 3) * XKSTR + pix * 16 + (c & 7) * 2]) = u.s;
    }
  }

  // wave tile: 64 co (wm) x 64 px (rows wn*2, wn*2+1)
  const int lpx = lane & 31;
  const int lkh = lane >> 5;
  const int wm  = wv & 1;
  const int wn  = wv >> 1;    // 0..3

  f32x16 acc[2][2];
  #pragma unroll
  for (int mf = 0; mf < 2; ++mf)
    #pragma unroll
    for (int nf = 0; nf < 2; ++nf)
      acc[mf][nf] = (f32x16)(0.f);

  // A cell: Ws[ks*2+lkh][wm*64+mf*32+lpx];  B cell: Xs[ks*2+lkh][pixel]
  const int abase = lkh * 2048 + (wm * 64 + lpx) * 16;   // + mf*512 + ks*4096
  const int xbase = lkh * XKSTR;                          // + ks*2*XKSTR + pix*16

  __syncthreads();   // Xs + Ws[0] ready

  for (int t = 0; t < 9; ++t) {
    if (t < 8) {   // async-prefetch tap t+1 (buffer last read in tap t-1; barrier-safe)
      const unsigned short* sn = wt + (t + 1) * 8192 + lane * 8;
      unsigned char* db = Ws[(t + 1) & 1];
      #pragma unroll
      for (int j = 0; j < 2; ++j) {
        const int i = wv * 2 + j;
        gload_lds16(sn + i * 512, &db[i * 1024]);
      }
    }
    const int dy = (t >= 6) ? 2 : (t >= 3 ? 1 : 0);
    const int dx = t - dy * 3;
    const unsigned char* wsb = Ws[t & 1];
    int boff[2];
    #pragma unroll
    for (int nf = 0; nf < 2; ++nf)
      boff[nf] = xbase + ((wn * 2 + nf + dy) * HCOLS + dx + lpx) * 16;
    #pragma unroll
    for (int sh = 0; sh < 2; ++sh) {   // k-steps in batches of 2
      bf16x8 A[2][2], B[2][2];
      #pragma unroll
      for (int ss = 0; ss < 2; ++ss) {
        const int ks = sh * 2 + ss;
        #pragma unroll
        for (int mf = 0; mf < 2; ++mf)
          A[mf][ss] = *(const bf16x8*)&wsb[abase + mf * 512 + ks * 4096];
        #pragma unroll
        for (int nf = 0; nf < 2; ++nf)
          B[nf][ss] = *(const bf16x8*)&Xs[boff[nf] + ks * 2 * XKSTR];
      }
      __builtin_amdgcn_s_setprio(1);
      #pragma unroll
      for (int ss = 0; ss < 2; ++ss)
        #pragma unroll
        for (int mf = 0; mf < 2; ++mf)
          #pragma unroll
          for (int nf = 0; nf < 2; ++nf)
            acc[mf][nf] = __builtin_amdgcn_mfma_f32_32x32x16_bf16(A[mf][ss], B[nf][ss], acc[mf][nf], 0, 0, 0);
      __builtin_amdgcn_s_setprio(0);
    }
    __syncthreads();
  }

  // ---- epilogue: bias + fp32 full-line stores ----
  float4 bq[2][4];
  #pragma unroll
  for (int mf = 0; mf < 2; ++mf)
    #pragma unroll
    for (int rq = 0; rq < 4; ++rq)
      bq[mf][rq] = *(const float4*)(bias + wm * 64 + mf * 32 + rq * 8 + lkh * 4);

  #pragma unroll
  for (int nf = 0; nf < 2; ++nf) {
    const int y = gy0 + wn * 2 + nf;
    float* op = out + (size_t)img * C_OUT * HW + (size_t)y * Wimg + gx0 + lpx;
    #pragma unroll
    for (int mf = 0; mf < 2; ++mf) {
      #pragma unroll
      for (int r = 0; r < 16; ++r) {
        const int co = wm * 64 + mf * 32 + (r & 3) + 8 * (r >> 2) + lkh * 4;
        op[(size_t)co * HW] = acc[mf][nf][r] + ((const float*)&bq[mf][r >> 2])[r & 3];
      }
    }
  }
}

extern "C" void kernel_launch(void* const* d_in, const int* in_sizes, int n_in,
                              void* d_out, int out_size, void* d_ws, size_t ws_size,
                              hipStream_t stream) {
  const float* x    = (const float*)d_in[0];
  const float* w    = (const float*)d_in[1];
  const float* bias = (const float*)d_in[2];
  float* out = (float*)d_out;
  unsigned short* wt = (unsigned short*)d_ws;  // 9*8192 bf16 = 144 KB

  wt_transform<<<(9 * C_OUT * C_IN + 255) / 256, 256, 0, stream>>>(w, wt);

  conv_mfma<<<dim3(2304), 512, 0, stream>>>(x, wt, bias, out);
}